// Round 8
// baseline (220.881 us; speedup 1.0000x reference)
//
#include <hip/hip_runtime.h>

// SelfAttention: out = softmax(QK^T*s + fw)V + softmax(QK^T*s + bw)V
// B=8, L=2048, D=64, fp32 in/out. fp16 MFMA, no online max (scores bounded;
// -1e9 mask == hard zero in fp32 exp).
//
// v8: SAFE single kernel (no d_ws — every ws-reading design failed rigor:
// R5 post-timing divergence, R7 coop launch failure). Fixes v5's latency
// bound (10k cyc/iter @ 2 waves/SIMD, in-loop LDS V-transpose):
//   - NO LDS in main loop: V^T frags via direct scalar gathers from global
//     (the R5-prepack access pattern, numerics validated) + pkh. K frags via
//     row-contiguous float4 loads + pkh (v5 path).
//   - 512-thread WG: 8 waves x 256-key strips, 8 iters; grid 512
//     -> 16 waves/CU (4/SIMD) for latency hiding. launch_bounds(512,4).
//   - LDS only in epilogue: 43KB, 4-pass cross-wave reduction
//     (2 sides x 2 wave-halves over red[4][32][68]).
// Kept from v4/v5 (all HW-validated):
//   fp16 cvt_pkrtz; S^T = K·(Qs)^T via mfma_f32_16x16x32_f16; P fed DIRECTLY
//   into PV via mfma_f32_16x16x16f16 (S^T C-layout == K=16 B-operand layout);
//   XCD swizzle b = blockIdx&7; 32 q rows per WG.
//
// Layouts:
//   K=32 A: elem j of lane = A[col][quad*8+j]   B: B[quad*8+j][col]
//   K=16 A: elem j of lane = A[col][quad*4+j]   B: B[quad*4+j][col]
//   C/D:    elem r of lane = D[quad*4+r][col]

typedef __attribute__((ext_vector_type(8))) _Float16 half8;
typedef __attribute__((ext_vector_type(4))) _Float16 half4;
typedef __attribute__((ext_vector_type(4))) float f32x4;

union FragK { half8 h; unsigned u[4]; };
union FragV { half4 hv[2]; unsigned u[4]; };
union PFrag { half4 h; unsigned u[2]; };

#define MFMA32F(A, B, C) __builtin_amdgcn_mfma_f32_16x16x32_f16((A), (B), (C), 0, 0, 0)
#define MFMA16F(A, B, C) __builtin_amdgcn_mfma_f32_16x16x16f16((A), (B), (C), 0, 0, 0)

static constexpr int BB = 8, LL = 2048, DD = 64;
static constexpr float QSCALE = 0.125f * 1.44269504088896340736f;  // /sqrt(64)*log2(e)

__device__ __forceinline__ unsigned pkh(float a, float b) {
    auto h = __builtin_amdgcn_cvt_pkrtz(a, b);   // __fp16 ext_vector(2)
    return __builtin_bit_cast(unsigned, h);
}

__global__ __launch_bounds__(512, 4)
void attn_v8(const float* __restrict__ Q, const float* __restrict__ K,
             const float* __restrict__ V, float* __restrict__ O) {
    // Epilogue-only LDS: red[4 waves][32 q][68 d] = 8704 f ; lred[8][2][4][32]
    __shared__ __align__(16) float red[8704 + 2048];
    float* lred = red + 8704;

    const int tid  = threadIdx.x;
    const int w    = tid >> 6;          // 0..7
    const int lane = tid & 63;
    const int col  = lane & 15;
    const int quad = lane >> 4;

    const int b  = blockIdx.x & 7;          // batch == XCD slot
    const int i0 = (blockIdx.x >> 3) << 5;  // 32 q rows per WG

    const float* Qb = Q + (size_t)b * LL * DD;
    const float* Kb = K + (size_t)b * LL * DD;
    const float* Vb = V + (size_t)b * LL * DD;

    // ---- Q fragments (B operand of S^T), pre-scaled, one per 16-q tile
    FragK qf[2][2];
    #pragma unroll
    for (int t = 0; t < 2; ++t) {
        const float* qr = Qb + (size_t)(i0 + 16 * t + col) * DD + quad * 8;
        float4 a0 = *(const float4*)(qr + 0);
        float4 a1 = *(const float4*)(qr + 4);
        float4 a2 = *(const float4*)(qr + 32);
        float4 a3 = *(const float4*)(qr + 36);
        qf[t][0].u[0] = pkh(a0.x * QSCALE, a0.y * QSCALE);
        qf[t][0].u[1] = pkh(a0.z * QSCALE, a0.w * QSCALE);
        qf[t][0].u[2] = pkh(a1.x * QSCALE, a1.y * QSCALE);
        qf[t][0].u[3] = pkh(a1.z * QSCALE, a1.w * QSCALE);
        qf[t][1].u[0] = pkh(a2.x * QSCALE, a2.y * QSCALE);
        qf[t][1].u[1] = pkh(a2.z * QSCALE, a2.w * QSCALE);
        qf[t][1].u[2] = pkh(a3.x * QSCALE, a3.y * QSCALE);
        qf[t][1].u[3] = pkh(a3.z * QSCALE, a3.w * QSCALE);
    }

    const int kbase = w << 8;           // this wave's 256-key strip

    f32x4 zero = {0.f, 0.f, 0.f, 0.f};
    f32x4 ot[2][2][4];      // [tile][side][d-chunk]
    #pragma unroll
    for (int t = 0; t < 2; ++t)
        #pragma unroll
        for (int s = 0; s < 2; ++s)
            #pragma unroll
            for (int c = 0; c < 4; ++c) ot[t][s][c] = zero;
    float lsum[2][2] = {{0.f, 0.f}, {0.f, 0.f}};

    // ---- raw-load / pack helpers (per-wave, zero LDS) ----------------------
    auto loadK = [&](int j0, float4* kr4) {
        #pragma unroll
        for (int f = 0; f < 2; ++f) {
            const float* kr = Kb + (size_t)(j0 + 16 * f + col) * DD + quad * 8;
            kr4[f * 4 + 0] = *(const float4*)(kr + 0);
            kr4[f * 4 + 1] = *(const float4*)(kr + 4);
            kr4[f * 4 + 2] = *(const float4*)(kr + 32);
            kr4[f * 4 + 3] = *(const float4*)(kr + 36);
        }
    };
    auto packK = [&](const float4* kr4, FragK* kf) {
        #pragma unroll
        for (int f = 0; f < 2; ++f)
            #pragma unroll
            for (int h = 0; h < 2; ++h) {
                float4 x = kr4[f * 4 + 2 * h + 0];
                float4 y = kr4[f * 4 + 2 * h + 1];
                FragK& d = kf[f * 2 + h];
                d.u[0] = pkh(x.x, x.y);
                d.u[1] = pkh(x.z, x.w);
                d.u[2] = pkh(y.x, y.y);
                d.u[3] = pkh(y.z, y.w);
            }
    };
    // V^T gather straight into K=16 A-frag order (R5-prepack pattern):
    // frag c: keys j0+quad*4+j (hv[0]) and +16 (hv[1]) at d = 16c+col.
    auto loadV = [&](int j0, float* vr) {
        #pragma unroll
        for (int c = 0; c < 4; ++c) {
            const float* base = Vb + (size_t)(j0 + quad * 4) * DD + 16 * c + col;
            #pragma unroll
            for (int j = 0; j < 4; ++j) {
                vr[c * 8 + j]     = base[(size_t)(j * DD)];
                vr[c * 8 + 4 + j] = base[(size_t)((16 + j) * DD)];
            }
        }
    };
    auto packV = [&](const float* vr, FragV* vf) {
        #pragma unroll
        for (int c = 0; c < 4; ++c) {
            vf[c].u[0] = pkh(vr[c * 8 + 0], vr[c * 8 + 1]);
            vf[c].u[1] = pkh(vr[c * 8 + 2], vr[c * 8 + 3]);
            vf[c].u[2] = pkh(vr[c * 8 + 4], vr[c * 8 + 5]);
            vf[c].u[3] = pkh(vr[c * 8 + 6], vr[c * 8 + 7]);
        }
    };

    // ---- prologue: block 0
    FragK kfr[4];
    FragV vfr[4];
    {
        float4 kraw[8];
        float  vraw[32];
        loadK(kbase, kraw);
        loadV(kbase, vraw);
        packK(kraw, kfr);
        packV(vraw, vfr);
    }

    for (int blk = 0; blk < 8; ++blk) {
        const int j0 = kbase + (blk << 5);
        const int jn = (blk == 7) ? kbase : (j0 + 32);  // dummy last iter
        float4 krawN[8];
        float  vrawN[32];
        loadK(jn, krawN);
        loadV(jn, vrawN);

        const bool mixed = (j0 == i0);
        const bool doF   = (j0 >= i0);
        const bool doB   = (j0 <= i0);

        #pragma unroll
        for (int t = 0; t < 2; ++t) {
            // S^T = K · (Qs)^T : st0 = keys j0..+15, st1 = +16
            f32x4 st0 = zero, st1 = zero;
            st0 = MFMA32F(kfr[0].h, qf[t][0].h, st0);
            st0 = MFMA32F(kfr[1].h, qf[t][1].h, st0);
            st1 = MFMA32F(kfr[2].h, qf[t][0].h, st1);
            st1 = MFMA32F(kfr[3].h, qf[t][1].h, st1);

            float p0[4], p1[4];
            #pragma unroll
            for (int r = 0; r < 4; ++r) {
                p0[r] = __builtin_amdgcn_exp2f(st0[r]);
                p1[r] = __builtin_amdgcn_exp2f(st1[r]);
            }

            if (doF) {
                float m0[4], m1[4];
                if (mixed) {
                    const int ig = i0 + 16 * t + col;
                    #pragma unroll
                    for (int r = 0; r < 4; ++r) {
                        const int jg = j0 + 4 * quad + r;
                        m0[r] = (jg >= ig) ? p0[r] : 0.f;
                        m1[r] = (jg + 16 >= ig) ? p1[r] : 0.f;
                    }
                } else {
                    #pragma unroll
                    for (int r = 0; r < 4; ++r) { m0[r] = p0[r]; m1[r] = p1[r]; }
                }
                lsum[t][0] += m0[0] + m0[1] + m0[2] + m0[3] + m1[0] + m1[1] + m1[2] + m1[3];
                PFrag f0, f1;
                f0.u[0] = pkh(m0[0], m0[1]); f0.u[1] = pkh(m0[2], m0[3]);
                f1.u[0] = pkh(m1[0], m1[1]); f1.u[1] = pkh(m1[2], m1[3]);
                #pragma unroll
                for (int c = 0; c < 4; ++c) {
                    ot[t][0][c] = MFMA16F(vfr[c].hv[0], f0.h, ot[t][0][c]);
                    ot[t][0][c] = MFMA16F(vfr[c].hv[1], f1.h, ot[t][0][c]);
                }
            }
            if (doB) {
                float m0[4], m1[4];
                if (mixed) {
                    const int ig = i0 + 16 * t + col;
                    #pragma unroll
                    for (int r = 0; r < 4; ++r) {
                        const int jg = j0 + 4 * quad + r;
                        m0[r] = (jg <= ig) ? p0[r] : 0.f;
                        m1[r] = (jg + 16 <= ig) ? p1[r] : 0.f;
                    }
                } else {
                    #pragma unroll
                    for (int r = 0; r < 4; ++r) { m0[r] = p0[r]; m1[r] = p1[r]; }
                }
                lsum[t][1] += m0[0] + m0[1] + m0[2] + m0[3] + m1[0] + m1[1] + m1[2] + m1[3];
                PFrag g0, g1;
                g0.u[0] = pkh(m0[0], m0[1]); g0.u[1] = pkh(m0[2], m0[3]);
                g1.u[0] = pkh(m1[0], m1[1]); g1.u[1] = pkh(m1[2], m1[3]);
                #pragma unroll
                for (int c = 0; c < 4; ++c) {
                    ot[t][1][c] = MFMA16F(vfr[c].hv[0], g0.h, ot[t][1][c]);
                    ot[t][1][c] = MFMA16F(vfr[c].hv[1], g1.h, ot[t][1][c]);
                }
            }
        }

        packK(krawN, kfr);
        packV(vrawN, vfr);
    }

    // ---- epilogue: 4-pass cross-wave reduction (2 sides x 2 wave-halves) --
    #pragma unroll
    for (int t = 0; t < 2; ++t)
        #pragma unroll
        for (int s = 0; s < 2; ++s)
            lred[((w * 2 + s) * 4 + quad) * 32 + 16 * t + col] = lsum[t][s];

    const int qo = tid >> 4;            // 0..31
    const int d0 = (tid & 15) << 2;     // 0..60
    float lf = 0.f, lb = 0.f;
    f32x4 accF = zero, accB = zero;
    #pragma unroll
    for (int s = 0; s < 2; ++s) {
        f32x4 a = zero;
        #pragma unroll
        for (int h = 0; h < 2; ++h) {
            if ((w >> 2) == h) {
                #pragma unroll
                for (int t = 0; t < 2; ++t)
                    #pragma unroll
                    for (int c = 0; c < 4; ++c)
                        *(f32x4*)&red[((w & 3) * 32 + 16 * t + col) * 68 + 16 * c + 4 * quad] = ot[t][s][c];
            }
            __syncthreads();
            if (s == 0 && h == 0) {
                #pragma unroll
                for (int w2 = 0; w2 < 8; ++w2)
                    #pragma unroll
                    for (int qd = 0; qd < 4; ++qd) {
                        lf += lred[((w2 * 2 + 0) * 4 + qd) * 32 + qo];
                        lb += lred[((w2 * 2 + 1) * 4 + qd) * 32 + qo];
                    }
            }
            #pragma unroll
            for (int w2 = 0; w2 < 4; ++w2)
                a += *(const f32x4*)&red[(w2 * 32 + qo) * 68 + d0];
            __syncthreads();
        }
        if (s == 0) accF = a; else accB = a;
    }

    const float rf = 1.0f / lf;
    const float rb = 1.0f / lb;
    float4 o = {accF[0] * rf + accB[0] * rb, accF[1] * rf + accB[1] * rb,
                accF[2] * rf + accB[2] * rb, accF[3] * rf + accB[3] * rb};
    *(float4*)(O + ((size_t)(b * LL) + i0 + qo) * DD + d0) = o;
}

extern "C" void kernel_launch(void* const* d_in, const int* in_sizes, int n_in,
                              void* d_out, int out_size, void* d_ws, size_t ws_size,
                              hipStream_t stream) {
    const float* q = (const float*)d_in[0];
    const float* k = (const float*)d_in[1];
    const float* v = (const float*)d_in[2];
    float* o = (float*)d_out;
    (void)in_sizes; (void)n_in; (void)out_size; (void)d_ws; (void)ws_size;
    attn_v8<<<dim3(512), dim3(512), 0, stream>>>(q, k, v, o);
}